// Round 2
// baseline (3563.285 us; speedup 1.0000x reference)
//
#include <hip/hip_runtime.h>

#define NHEAD 16
#define DHEAD 64
#define XLEN 1024
#define MEMLEN 1024
#define BATCH 4
#define TOT 2048
#define DFF 4096
#define DM 1024

// ---------------- fp32 GEMM, 128x128 tile, 8x8 per thread, fused epilogues ----
#define BM 128
#define BN 128
#define BK 16

template<int MODE>
__global__ __launch_bounds__(256) void gemm_k(
    const float* __restrict__ A0, const float* __restrict__ A1, int splitRow,
    const float* __restrict__ Bm, int N, int K,
    const float* __restrict__ e0, const float* __restrict__ e1,
    float* __restrict__ o0, float* __restrict__ o1)
{
  __shared__ float As[BK][BM];   // k-major
  __shared__ float Bs[BK][BN];
  const int t = threadIdx.x;
  const int tx = t & 15, ty = t >> 4;          // 16x16 thread grid, 8x8 each
  const int m0 = blockIdx.y * BM, n0 = blockIdx.x * BN;
  const int ar = t >> 1, ac = (t & 1) * 8;     // A: 128 rows x 16 k, 8 floats/thread
  const int br = t >> 4, bc = (t & 15) * 8;    // B: 16 k x 128 cols, 8 floats/thread
  const int grow = m0 + ar;
  const float* Ap = (grow < splitRow) ? (A0 + (size_t)grow * K)
                                      : (A1 + (size_t)(grow - splitRow) * K);
  float acc[8][8] = {};
  for (int k0 = 0; k0 < K; k0 += BK) {
    float4 av0 = *(const float4*)(Ap + k0 + ac);
    float4 av1 = *(const float4*)(Ap + k0 + ac + 4);
    float4 bv0 = *(const float4*)(Bm + (size_t)(k0 + br) * N + n0 + bc);
    float4 bv1 = *(const float4*)(Bm + (size_t)(k0 + br) * N + n0 + bc + 4);
    As[ac + 0][ar] = av0.x; As[ac + 1][ar] = av0.y;
    As[ac + 2][ar] = av0.z; As[ac + 3][ar] = av0.w;
    As[ac + 4][ar] = av1.x; As[ac + 5][ar] = av1.y;
    As[ac + 6][ar] = av1.z; As[ac + 7][ar] = av1.w;
    *(float4*)&Bs[br][bc] = bv0;
    *(float4*)&Bs[br][bc + 4] = bv1;
    __syncthreads();
#pragma unroll
    for (int k = 0; k < BK; ++k) {
      float4 a0 = *(const float4*)&As[k][ty * 8];
      float4 a1 = *(const float4*)&As[k][ty * 8 + 4];
      float4 b0 = *(const float4*)&Bs[k][tx * 8];
      float4 b1 = *(const float4*)&Bs[k][tx * 8 + 4];
      float aa[8] = {a0.x, a0.y, a0.z, a0.w, a1.x, a1.y, a1.z, a1.w};
      float bb[8] = {b0.x, b0.y, b0.z, b0.w, b1.x, b1.y, b1.z, b1.w};
#pragma unroll
      for (int i = 0; i < 8; ++i)
#pragma unroll
        for (int j = 0; j < 8; ++j)
          acc[i][j] += aa[i] * bb[j];
    }
    __syncthreads();
  }
#pragma unroll
  for (int i = 0; i < 8; ++i) {
    int m = m0 + ty * 8 + i;
#pragma unroll
    for (int j = 0; j < 8; ++j) {
      int nn = n0 + tx * 8 + j;
      float v = acc[i][j];
      if (MODE == 0) {           // c@Wkv -> K^T [B,N,Dh,T], V [B,N,T,Dh]
        int tt = m >> 2, b = m & 3;
        if (nn < NHEAD * DHEAD) {
          int hn = nn >> 6, d = nn & 63;
          o0[((size_t)(b * NHEAD + hn) * DHEAD + d) * TOT + tt] = v;
        } else {
          int c2 = nn - NHEAD * DHEAD;
          int hn = c2 >> 6, d = c2 & 63;
          o1[((size_t)(b * NHEAD + hn) * TOT + tt) * DHEAD + d] = v;
        }
      } else if (MODE == 1) {    // x@Wq -> Qu,Qv [B,N,I,Dh] (+pos_bias_u/v)
        int i2 = m >> 2, b = m & 3;
        int hn = nn >> 6, d = nn & 63;
        size_t oi = ((size_t)(b * NHEAD + hn) * XLEN + i2) * DHEAD + d;
        o0[oi] = v + e0[nn];
        o1[oi] = v + e1[nn];
      } else if (MODE == 2) {    // pos@Wrel -> R^T [B,N,Dh,T]
        int tt = m >> 2, b = m & 3;
        int hn = nn >> 6, d = nn & 63;
        o0[((size_t)(b * NHEAD + hn) * DHEAD + d) * TOT + tt] = v;
      } else if (MODE == 3) {    // vec@Wo + x
        o0[(size_t)m * N + nn] = v + e0[(size_t)m * N + nn];
      } else if (MODE == 4) {    // relu(h@W1 + b1)
        o0[(size_t)m * N + nn] = fmaxf(v + e0[nn], 0.f);
      } else if (MODE == 5) {    // ff@W2 + b2 + h
        o0[(size_t)m * N + nn] = v + e0[nn] + e1[(size_t)m * N + nn];
      }
    }
  }
}

// ---------------- attention ----------------
// block = (i_tile of 8 query rows, batch b); loops over 16 heads.
// LDS: sc[8][2048] score/prob rows + q tiles. ~68KB -> 2 blocks/CU.
#define TI 8

__global__ __launch_bounds__(256) void attn_k(
    const float* __restrict__ Qu, const float* __restrict__ Qv,
    const float* __restrict__ KT, const float* __restrict__ V,
    const float* __restrict__ RT,
    float* __restrict__ vec, float* __restrict__ attnacc)
{
  __shared__ float sc[TI][TOT];
  __shared__ float qu[TI][DHEAD];
  __shared__ float qv[TI][DHEAD];
  __shared__ float red[TI];
  const int i0 = blockIdx.x * TI;
  const int b  = blockIdx.y;
  const int t  = threadIdx.x;
  const float scale = 0.125f;  // 1/sqrt(64)
  float* ap = attnacc + ((size_t)b * XLEN + i0) * TOT;

  for (int n = 0; n < NHEAD; ++n) {
    const int ho = b * NHEAD + n;
    {  // load q tiles (8x64 each, contiguous)
      const float* qup = Qu + ((size_t)ho * XLEN + i0) * DHEAD;
      const float* qvp = Qv + ((size_t)ho * XLEN + i0) * DHEAD;
      for (int idx = t; idx < TI * DHEAD; idx += 256) {
        (&qu[0][0])[idx] = qup[idx];
        (&qv[0][0])[idx] = qvp[idx];
      }
    }
    __syncthreads();

    // ---- D pass: D[ti][jj] = Qv[ti] . R[:,jj] -> sc[ti][jj + i - 1023]
    const float* Rb = RT + (size_t)ho * DHEAD * TOT;
    for (int c = 0; c < 2; ++c) {
      const int jj = c * 1024 + t * 4;
      float4 a[TI];
#pragma unroll
      for (int ti = 0; ti < TI; ++ti) a[ti] = make_float4(0.f, 0.f, 0.f, 0.f);
      const float* rp = Rb + jj;
#pragma unroll 4
      for (int d = 0; d < DHEAD; ++d) {
        float4 rv = *(const float4*)(rp + (size_t)d * TOT);
#pragma unroll
        for (int ti = 0; ti < TI; ++ti) {
          float q = qv[ti][d];
          a[ti].x += q * rv.x; a[ti].y += q * rv.y;
          a[ti].z += q * rv.z; a[ti].w += q * rv.w;
        }
      }
#pragma unroll
      for (int ti = 0; ti < TI; ++ti) {
        int j0 = jj + (i0 + ti) - (XLEN - 1);  // j = jj + i - 1023
        if (j0 + 0 >= 0) sc[ti][j0 + 0] = a[ti].x;
        if (j0 + 1 >= 0) sc[ti][j0 + 1] = a[ti].y;
        if (j0 + 2 >= 0) sc[ti][j0 + 2] = a[ti].z;
        if (j0 + 3 >= 0) sc[ti][j0 + 3] = a[ti].w;
      }
    }
    __syncthreads();

    // ---- AC pass + combine + mask + scale
    const float* Kb = KT + (size_t)ho * DHEAD * TOT;
    for (int c = 0; c < 2; ++c) {
      const int j = c * 1024 + t * 4;
      float4 a[TI];
#pragma unroll
      for (int ti = 0; ti < TI; ++ti) a[ti] = make_float4(0.f, 0.f, 0.f, 0.f);
      const float* kp = Kb + j;
#pragma unroll 4
      for (int d = 0; d < DHEAD; ++d) {
        float4 kv = *(const float4*)(kp + (size_t)d * TOT);
#pragma unroll
        for (int ti = 0; ti < TI; ++ti) {
          float q = qu[ti][d];
          a[ti].x += q * kv.x; a[ti].y += q * kv.y;
          a[ti].z += q * kv.z; a[ti].w += q * kv.w;
        }
      }
#pragma unroll
      for (int ti = 0; ti < TI; ++ti) {
        const int lim = i0 + ti + MEMLEN;  // masked when j > lim
        float4 dv = *(const float4*)&sc[ti][j];
        float4 o;
        o.x = (j + 0 <= lim) ? (a[ti].x + dv.x) * scale : -1e30f;
        o.y = (j + 1 <= lim) ? (a[ti].y + dv.y) * scale : -1e30f;
        o.z = (j + 2 <= lim) ? (a[ti].z + dv.z) * scale : -1e30f;
        o.w = (j + 3 <= lim) ? (a[ti].w + dv.w) * scale : -1e30f;
        *(float4*)&sc[ti][j] = o;
      }
    }
    __syncthreads();

    // ---- softmax: wave w handles rows w and w+4
    {
      const int wv = t >> 6, lane = t & 63;
#pragma unroll
      for (int rr = 0; rr < 2; ++rr) {
        const int ti = wv + rr * 4;
        float m = -1e30f;
        for (int j = lane; j < TOT; j += 64) m = fmaxf(m, sc[ti][j]);
#pragma unroll
        for (int off = 32; off; off >>= 1) m = fmaxf(m, __shfl_xor(m, off));
        float l = 0.f;
        for (int j = lane; j < TOT; j += 64) {
          float e = __expf(sc[ti][j] - m);
          sc[ti][j] = e;
          l += e;
        }
#pragma unroll
        for (int off = 32; off; off >>= 1) l += __shfl_xor(l, off);
        if (lane == 0) red[ti] = 1.0f / l;
      }
    }
    __syncthreads();

    // ---- attn-matrix accumulation (block-owned region, no atomics)
    for (int idx = t; idx < TI * TOT; idx += 256) {
      int ti = idx >> 11;
      float p = sc[ti][idx & (TOT - 1)] * red[ti];
      if (n == 0) ap[idx] = p; else ap[idx] += p;
    }

    // ---- PV: V read once per block-head; 8 rows accumulated per lane
    float pv[TI];
#pragma unroll
    for (int ti = 0; ti < TI; ++ti) pv[ti] = 0.f;
    {
      const int q = t >> 6, d = t & 63;
      const float* vp = V + (size_t)ho * TOT * DHEAD + d;
      for (int jb = 0; jb < TOT / 4; ++jb) {
        int j = jb * 4 + q;
        float vv = vp[(size_t)j * DHEAD];
#pragma unroll
        for (int ti = 0; ti < TI; ++ti) pv[ti] += sc[ti][j] * vv;
      }
    }
    __syncthreads();  // all sc reads done
    {  // stage per-wave partials into sc region, reduce across 4 waves
      const int q = t >> 6, d = t & 63;
      float* stg = &sc[0][0];
#pragma unroll
      for (int ti = 0; ti < TI; ++ti) stg[(q * TI + ti) * DHEAD + d] = pv[ti];
    }
    __syncthreads();
    {
      float* stg = &sc[0][0];
      for (int idx = t; idx < TI * DHEAD; idx += 256) {
        int ti = idx >> 6, d = idx & 63;
        float s = stg[ti * DHEAD + d] + stg[(TI + ti) * DHEAD + d] +
                  stg[(2 * TI + ti) * DHEAD + d] + stg[(3 * TI + ti) * DHEAD + d];
        vec[((size_t)(i0 + ti) * BATCH + b) * (NHEAD * DHEAD) + n * DHEAD + d] =
            s * red[ti];
      }
    }
    __syncthreads();
  }
}

// ---------------- attn matrix finalize: mean over batch ----------------
__global__ __launch_bounds__(256) void attnfin_k(const float* __restrict__ acc,
                                                 float* __restrict__ out)
{
  size_t idx = (size_t)blockIdx.x * 256 + threadIdx.x;  // 2M elements
  const size_t S = (size_t)XLEN * TOT;
  float s = acc[idx] + acc[idx + S] + acc[idx + 2 * S] + acc[idx + 3 * S];
  out[idx] = s * (1.0f / 64.0f);
}

// ---------------- LayerNorm (one block per row of 1024) ----------------
__global__ __launch_bounds__(256) void ln_k(const float* __restrict__ in,
                                            const float* __restrict__ g,
                                            const float* __restrict__ bb,
                                            float* __restrict__ out)
{
  __shared__ float rbuf[8];
  const int row = blockIdx.x;
  const int t = threadIdx.x;
  const float* p = in + (size_t)row * DM;
  float4 v = *(const float4*)(p + t * 4);
  float s1 = v.x + v.y + v.z + v.w;
  float s2 = v.x * v.x + v.y * v.y + v.z * v.z + v.w * v.w;
#pragma unroll
  for (int off = 32; off; off >>= 1) {
    s1 += __shfl_xor(s1, off);
    s2 += __shfl_xor(s2, off);
  }
  const int wv = t >> 6, lane = t & 63;
  if (lane == 0) { rbuf[wv] = s1; rbuf[4 + wv] = s2; }
  __syncthreads();
  if (t == 0) {
    float a = rbuf[0] + rbuf[1] + rbuf[2] + rbuf[3];
    float b2 = rbuf[4] + rbuf[5] + rbuf[6] + rbuf[7];
    float mu = a * (1.f / DM);
    float var = b2 * (1.f / DM) - mu * mu;
    rbuf[0] = mu;
    rbuf[1] = rsqrtf(var + 1e-5f);
  }
  __syncthreads();
  float mu = rbuf[0], rs = rbuf[1];
  float4 gv = *(const float4*)(g + t * 4);
  float4 bv = *(const float4*)(bb + t * 4);
  float4 o;
  o.x = (v.x - mu) * rs * gv.x + bv.x;
  o.y = (v.y - mu) * rs * gv.y + bv.y;
  o.z = (v.z - mu) * rs * gv.z + bv.z;
  o.w = (v.w - mu) * rs * gv.w + bv.w;
  *(float4*)(out + (size_t)row * DM + t * 4) = o;
}

// ---------------- launch ----------------
extern "C" void kernel_launch(void* const* d_in, const int* in_sizes, int n_in,
                              void* d_out, int out_size, void* d_ws, size_t ws_size,
                              hipStream_t stream) {
  const float* x      = (const float*)d_in[0];
  const float* memory = (const float*)d_in[1];
  const float* pos    = (const float*)d_in[2];
  const float* pbu    = (const float*)d_in[3];
  const float* pbv    = (const float*)d_in[4];
  // d_in[5] = mask (deterministic; computed analytically in-kernel)
  const float* Wq   = (const float*)d_in[6];
  const float* Wkv  = (const float*)d_in[7];
  const float* Wrel = (const float*)d_in[8];
  const float* Wo   = (const float*)d_in[9];
  const float* ln1g = (const float*)d_in[10];
  const float* ln1b = (const float*)d_in[11];
  const float* W1   = (const float*)d_in[12];
  const float* b1   = (const float*)d_in[13];
  const float* W2   = (const float*)d_in[14];
  const float* b2   = (const float*)d_in[15];
  const float* ln2g = (const float*)d_in[16];
  const float* ln2b = (const float*)d_in[17];

  float* out   = (float*)d_out;                    // [1024,4,1024]
  float* attnm = out + (size_t)XLEN * BATCH * DM;  // [1024,2048]
  float* ws = (float*)d_ws;

  // workspace layout (floats)
  float* KT      = ws + 0;           // [B,N,Dh,T]  8,388,608
  float* V       = ws + 8388608;     // [B,N,T,Dh]  8,388,608
  float* RT      = ws + 16777216;    // [B,N,Dh,T]  8,388,608
  float* Qu      = ws + 25165824;    // [B,N,I,Dh]  4,194,304
  float* Qv      = ws + 29360128;    // [B,N,I,Dh]  4,194,304
  float* vec     = ws + 33554432;    // [I,B,N*Dh]  4,194,304
  float* t1      = ws + 37748736;    // [I*B, D]    4,194,304
  float* h       = ws + 41943040;    // [I*B, D]    4,194,304
  float* attnacc = ws + 46137344;    // [B,I,T]     8,388,608
  float* ffp     = ws + 0;           // [I*B, DFF] 16,777,216 (aliases KT+V, dead by then)
  float* t2      = t1;               // t1 dead after LN1

  const int BIG = 1 << 30;

  // 1) K,V  (c = [memory; x] rows t*B+b, split at 4096)
  gemm_k<0><<<dim3(2048 / BN, 8192 / BM), 256, 0, stream>>>(
      memory, x, MEMLEN * BATCH, Wkv, 2048, DM, nullptr, nullptr, KT, V);
  // 2) R^T
  gemm_k<2><<<dim3(1024 / BN, 8192 / BM), 256, 0, stream>>>(
      pos, pos, BIG, Wrel, 1024, DM, nullptr, nullptr, RT, nullptr);
  // 3) Qu, Qv
  gemm_k<1><<<dim3(1024 / BN, 4096 / BM), 256, 0, stream>>>(
      x, x, BIG, Wq, 1024, DM, pbu, pbv, Qu, Qv);
  // 4) attention
  attn_k<<<dim3(XLEN / TI, BATCH), 256, 0, stream>>>(Qu, Qv, KT, V, RT, vec, attnacc);
  // 5) attn matrix mean over batch
  attnfin_k<<<(XLEN * TOT) / 256, 256, 0, stream>>>(attnacc, attnm);
  // 6) attn_out = vec@Wo + x
  gemm_k<3><<<dim3(1024 / BN, 4096 / BM), 256, 0, stream>>>(
      vec, vec, BIG, Wo, 1024, DM, x, nullptr, t1, nullptr);
  // 7) h = LN1(t1)
  ln_k<<<XLEN * BATCH, 256, 0, stream>>>(t1, ln1g, ln1b, h);
  // 8) ff = relu(h@W1 + b1)
  gemm_k<4><<<dim3(DFF / BN, 4096 / BM), 256, 0, stream>>>(
      h, h, BIG, W1, DFF, DM, b1, nullptr, ffp, nullptr);
  // 9) t2 = ff@W2 + b2 + h
  gemm_k<5><<<dim3(1024 / BN, 4096 / BM), 256, 0, stream>>>(
      ffp, ffp, BIG, W2, 1024, DFF, b2, h, t2, nullptr);
  // 10) out = LN2(t2)
  ln_k<<<XLEN * BATCH, 256, 0, stream>>>(t2, ln2g, ln2b, out);
}

// Round 4
// 2123.714 us; speedup vs baseline: 1.6779x; 1.6779x over previous
//
#include <hip/hip_runtime.h>

#define NHEAD 16
#define DHEAD 64
#define XLEN 1024
#define MEMLEN 1024
#define BATCH 4
#define TOT 2048
#define DFF 4096
#define DM 1024

typedef __attribute__((ext_vector_type(8))) short bf16x8;
typedef __attribute__((ext_vector_type(4))) float f32x4;

__device__ __forceinline__ unsigned short bf16rn(float x) {
  union { float f; unsigned u; } c{x};
  unsigned r = c.u + 0x7fffu + ((c.u >> 16) & 1u);
  return (unsigned short)(r >> 16);
}
__device__ __forceinline__ float bf16tof(unsigned short h) {
  union { unsigned u; float f; } c{(unsigned)h << 16};
  return c.f;
}

#define GLOAD_LDS16(gp, lp)                                                    \
  __builtin_amdgcn_global_load_lds(                                            \
      (const __attribute__((address_space(1))) unsigned int*)(gp),             \
      (__attribute__((address_space(3))) unsigned int*)(lp), 16, 0, 0)

// ---------------- elementwise split: fp32 -> bf16 hi + bf16 lo --------------
__global__ __launch_bounds__(256) void split2_k(
    const float* __restrict__ s0, const float* __restrict__ s1, int splitElems,
    unsigned short* __restrict__ oh, unsigned short* __restrict__ ol)
{
  int i4 = (blockIdx.x * 256 + threadIdx.x) * 4;
  const float* src = (i4 < splitElems) ? (s0 + i4) : (s1 + (i4 - splitElems));
  float4 v = *(const float4*)src;
  ushort4 h, l;
  h.x = bf16rn(v.x); l.x = bf16rn(v.x - bf16tof(h.x));
  h.y = bf16rn(v.y); l.y = bf16rn(v.y - bf16tof(h.y));
  h.z = bf16rn(v.z); l.z = bf16rn(v.z - bf16tof(h.z));
  h.w = bf16rn(v.w); l.w = bf16rn(v.w - bf16tof(h.w));
  *(ushort4*)(oh + i4) = h;
  *(ushort4*)(ol + i4) = l;
}

// ------------- transpose + split: W[K][N] fp32 -> Wt hi/lo [N][K] bf16 ------
__global__ __launch_bounds__(256) void tsplit_k(
    const float* __restrict__ W, int K, int N,
    unsigned short* __restrict__ oh, unsigned short* __restrict__ ol)
{
  __shared__ float tile[64][65];
  const int t = threadIdx.x;
  const int bk = blockIdx.x * 64, bn = blockIdx.y * 64;
#pragma unroll
  for (int r = 0; r < 4; ++r) {
    int lr = r * 16 + (t >> 4), lc = (t & 15) * 4;
    *(float4*)&tile[lr][lc] = *(const float4*)&W[(size_t)(bk + lr) * N + bn + lc];
  }
  __syncthreads();
  const int n = t >> 2, kq = t & 3;
  unsigned short* ph = oh + (size_t)(bn + n) * K + bk + kq * 16;
  unsigned short* pl = ol + (size_t)(bn + n) * K + bk + kq * 16;
#pragma unroll
  for (int c = 0; c < 4; ++c) {
    ushort4 h, l;
    float v0 = tile[kq * 16 + c * 4 + 0][n];
    float v1 = tile[kq * 16 + c * 4 + 1][n];
    float v2 = tile[kq * 16 + c * 4 + 2][n];
    float v3 = tile[kq * 16 + c * 4 + 3][n];
    h.x = bf16rn(v0); l.x = bf16rn(v0 - bf16tof(h.x));
    h.y = bf16rn(v1); l.y = bf16rn(v1 - bf16tof(h.y));
    h.z = bf16rn(v2); l.z = bf16rn(v2 - bf16tof(h.z));
    h.w = bf16rn(v3); l.w = bf16rn(v3 - bf16tof(h.w));
    *(ushort4*)(ph + c * 4) = h;
    *(ushort4*)(pl + c * 4) = l;
  }
}

// ---------------- MFMA GEMM: C = A(fp32 via hi/lo bf16) * B, 128x128 tile ---
// A: [M][K] as Ah/Al bf16 row-major. B: [N][K] as Bh/Bl bf16 (pre-transposed).
// 3-term Markidis: Ah*Bh + Ah*Bl + Al*Bh (fp32-equivalent accuracy).
// LDS tiles [128][32] bf16, slot-XOR swizzled (rule #21: linear gload_lds dest,
// pre-swizzled global source, swizzled ds_read).
template<int MODE>
__global__ __launch_bounds__(256) void gemm_k(
    const unsigned short* __restrict__ Ah, const unsigned short* __restrict__ Al,
    const unsigned short* __restrict__ Bh, const unsigned short* __restrict__ Bl,
    int N, int K,
    const float* __restrict__ e0, const float* __restrict__ e1,
    float* __restrict__ o0, float* __restrict__ o1,
    unsigned short* __restrict__ p0, unsigned short* __restrict__ p1)
{
  __shared__ unsigned short lds[4][4096];  // Ah,Al,Bh,Bl: 128 rows x 32 bf16
  const int t = threadIdx.x;
  const int wave = t >> 6, lane = t & 63;
  const int wm = wave >> 1, wn = wave & 1;   // 2x2 wave grid, 64x64 per wave
  const int m0 = blockIdx.y * 128, n0 = blockIdx.x * 128;

  // staging geometry: slot s = iter*256 + t; row = s>>2; slot4 = s&3 (16B units)
  // global source pre-swizzled: col16 = slot4 ^ (row&3)
  const unsigned short* gp[2][4];  // [iter][arr]
  unsigned short* lp[2][4];
#pragma unroll
  for (int i = 0; i < 2; ++i) {
    int s = i * 256 + t, row = s >> 2, sl = s & 3;
    int csw = (sl ^ (row & 3)) * 8;
    gp[i][0] = Ah + (size_t)(m0 + row) * K + csw;
    gp[i][1] = Al + (size_t)(m0 + row) * K + csw;
    gp[i][2] = Bh + (size_t)(n0 + row) * K + csw;
    gp[i][3] = Bl + (size_t)(n0 + row) * K + csw;
#pragma unroll
    for (int a = 0; a < 4; ++a) lp[i][a] = &lds[a][s * 8];
  }

  f32x4 acc[4][4] = {};
  const int kg = lane >> 4, r15 = lane & 15;

  for (int k0 = 0; k0 < K; k0 += 32) {
#pragma unroll
    for (int i = 0; i < 2; ++i)
#pragma unroll
      for (int a = 0; a < 4; ++a) GLOAD_LDS16(gp[i][a] + k0, lp[i][a]);
    __syncthreads();  // drains vmcnt(0): tiles ready

    bf16x8 afh[4], afl[4], bfh[4], bfl[4];
#pragma unroll
    for (int f = 0; f < 4; ++f) {
      int rowA = wm * 64 + f * 16 + r15;
      int ia = (rowA * 4 + (kg ^ (rowA & 3))) * 8;
      afh[f] = *(const bf16x8*)&lds[0][ia];
      afl[f] = *(const bf16x8*)&lds[1][ia];
      int rowB = wn * 64 + f * 16 + r15;
      int ib = (rowB * 4 + (kg ^ (rowB & 3))) * 8;
      bfh[f] = *(const bf16x8*)&lds[2][ib];
      bfl[f] = *(const bf16x8*)&lds[3][ib];
    }
#pragma unroll
    for (int i = 0; i < 4; ++i)
#pragma unroll
      for (int j = 0; j < 4; ++j) {
        acc[i][j] = __builtin_amdgcn_mfma_f32_16x16x32_bf16(afh[i], bfh[j], acc[i][j], 0, 0, 0);
        acc[i][j] = __builtin_amdgcn_mfma_f32_16x16x32_bf16(afh[i], bfl[j], acc[i][j], 0, 0, 0);
        acc[i][j] = __builtin_amdgcn_mfma_f32_16x16x32_bf16(afl[i], bfh[j], acc[i][j], 0, 0, 0);
      }
    __syncthreads();  // readers done before next-stage overwrite
  }

  // epilogue: C/D layout col = lane&15, row = (lane>>4)*4 + reg  [m89-verified]
#pragma unroll
  for (int i = 0; i < 4; ++i)
#pragma unroll
    for (int j = 0; j < 4; ++j)
#pragma unroll
      for (int r = 0; r < 4; ++r) {
        int m = m0 + wm * 64 + i * 16 + kg * 4 + r;
        int nn = n0 + wn * 64 + j * 16 + r15;
        float v = acc[i][j][r];
        if (MODE == 0) {           // c@Wkv -> K^T [B,N,Dh,T], V [B,N,T,Dh]
          int tt = m >> 2, b = m & 3;
          if (nn < NHEAD * DHEAD) {
            int hn = nn >> 6, d = nn & 63;
            o0[((size_t)(b * NHEAD + hn) * DHEAD + d) * TOT + tt] = v;
          } else {
            int c2 = nn - NHEAD * DHEAD;
            int hn = c2 >> 6, d = c2 & 63;
            o1[((size_t)(b * NHEAD + hn) * TOT + tt) * DHEAD + d] = v;
          }
        } else if (MODE == 1) {    // x@Wq -> Qu,Qv [B,N,I,Dh] (+pos_bias)
          int i2 = m >> 2, b = m & 3;
          int hn = nn >> 6, d = nn & 63;
          size_t oi = ((size_t)(b * NHEAD + hn) * XLEN + i2) * DHEAD + d;
          o0[oi] = v + e0[nn];
          o1[oi] = v + e1[nn];
        } else if (MODE == 2) {    // pos@Wrel -> R^T [B,N,Dh,T]
          int tt = m >> 2, b = m & 3;
          int hn = nn >> 6, d = nn & 63;
          o0[((size_t)(b * NHEAD + hn) * DHEAD + d) * TOT + tt] = v;
        } else if (MODE == 3) {    // vec@Wo + x -> t1 (fp32)
          o0[(size_t)m * N + nn] = v + e0[(size_t)m * N + nn];
        } else if (MODE == 4) {    // relu(h@W1 + b1) -> ffp hi/lo bf16
          float v2 = fmaxf(v + e0[nn], 0.f);
          unsigned short hh = bf16rn(v2);
          p0[(size_t)m * N + nn] = hh;
          p1[(size_t)m * N + nn] = bf16rn(v2 - bf16tof(hh));
        } else if (MODE == 5) {    // ff@W2 + b2 + h -> t2 (fp32)
          o0[(size_t)m * N + nn] = v + e0[nn] + e1[(size_t)m * N + nn];
        }
      }
}

// ---------------- attention (fp32, 512 threads, full 2048-row per pass) -----
#define TI 8

__global__ __launch_bounds__(512) void attn_k(
    const float* __restrict__ Qu, const float* __restrict__ Qv,
    const float* __restrict__ KT, const float* __restrict__ V,
    const float* __restrict__ RT,
    float* __restrict__ vec, float* __restrict__ attnacc)
{
  __shared__ float sc[TI][TOT];
  __shared__ float qu[TI][DHEAD];
  __shared__ float qv[TI][DHEAD];
  __shared__ float red[TI];
  const int i0 = blockIdx.x * TI;
  const int b  = blockIdx.y;
  const int t  = threadIdx.x;
  const float scale = 0.125f;
  float* ap = attnacc + ((size_t)b * XLEN + i0) * TOT;

  for (int n = 0; n < NHEAD; ++n) {
    const int ho = b * NHEAD + n;
    {
      const float* qup = Qu + ((size_t)ho * XLEN + i0) * DHEAD;
      const float* qvp = Qv + ((size_t)ho * XLEN + i0) * DHEAD;
      if (t < TI * DHEAD) {
        (&qu[0][0])[t] = qup[t];
        (&qv[0][0])[t] = qvp[t];
      }
    }
    __syncthreads();

    // ---- D pass: D[ti][jj] = Qv[ti] . R[:,jj] -> sc[ti][jj + i - 1023]
    {
      const int jj = t * 4;
      const float* rp = RT + (size_t)ho * DHEAD * TOT + jj;
      float4 a[TI];
#pragma unroll
      for (int ti = 0; ti < TI; ++ti) a[ti] = make_float4(0.f, 0.f, 0.f, 0.f);
#pragma unroll 4
      for (int d = 0; d < DHEAD; ++d) {
        float4 rv = *(const float4*)(rp + (size_t)d * TOT);
#pragma unroll
        for (int ti = 0; ti < TI; ++ti) {
          float q = qv[ti][d];
          a[ti].x += q * rv.x; a[ti].y += q * rv.y;
          a[ti].z += q * rv.z; a[ti].w += q * rv.w;
        }
      }
#pragma unroll
      for (int ti = 0; ti < TI; ++ti) {
        int j0 = jj + (i0 + ti) - (XLEN - 1);
        if (j0 + 0 >= 0) sc[ti][j0 + 0] = a[ti].x;
        if (j0 + 1 >= 0) sc[ti][j0 + 1] = a[ti].y;
        if (j0 + 2 >= 0) sc[ti][j0 + 2] = a[ti].z;
        if (j0 + 3 >= 0) sc[ti][j0 + 3] = a[ti].w;
      }
    }
    __syncthreads();

    // ---- AC pass + combine + mask + scale
    {
      const int j = t * 4;
      const float* kp = KT + (size_t)ho * DHEAD * TOT + j;
      float4 a[TI];
#pragma unroll
      for (int ti = 0; ti < TI; ++ti) a[ti] = make_float4(0.f, 0.f, 0.f, 0.f);
#pragma unroll 4
      for (int d = 0; d < DHEAD; ++d) {
        float4 kv = *(const float4*)(kp + (size_t)d * TOT);
#pragma unroll
        for (int ti = 0; ti < TI; ++ti) {
          float q = qu[ti][d];
          a[ti].x += q * kv.x; a[ti].y += q * kv.y;
          a[ti].z += q * kv.z; a[ti].w += q * kv.w;
        }
      }
#pragma unroll
      for (int ti = 0; ti < TI; ++ti) {
        const int lim = i0 + ti + MEMLEN;
        float4 dv = *(const float4*)&sc[ti][j];
        float4 o;
        o.x = (j + 0 <= lim) ? (a[ti].x + dv.x) * scale : -1e30f;
        o.y = (j + 1 <= lim) ? (a[ti].y + dv.y) * scale : -1e30f;
        o.z = (j + 2 <= lim) ? (a[ti].z + dv.z) * scale : -1e30f;
        o.w = (j + 3 <= lim) ? (a[ti].w + dv.w) * scale : -1e30f;
        *(float4*)&sc[ti][j] = o;
      }
    }
    __syncthreads();

    // ---- softmax: wave w handles row w
    {
      const int ti = t >> 6, lane = t & 63;
      float m = -1e30f;
      for (int j = lane; j < TOT; j += 64) m = fmaxf(m, sc[ti][j]);
#pragma unroll
      for (int off = 32; off; off >>= 1) m = fmaxf(m, __shfl_xor(m, off));
      float l = 0.f;
      for (int j = lane; j < TOT; j += 64) {
        float e = __expf(sc[ti][j] - m);
        sc[ti][j] = e;
        l += e;
      }
#pragma unroll
      for (int off = 32; off; off >>= 1) l += __shfl_xor(l, off);
      if (lane == 0) red[ti] = 1.0f / l;
    }
    __syncthreads();

    // ---- attn-matrix accumulation (block-owned region)
    for (int idx = t; idx < TI * TOT; idx += 512) {
      int ti = idx >> 11;
      float p = sc[idx >> 11][idx & (TOT - 1)] * red[ti];
      if (n == 0) ap[idx] = p; else ap[idx] += p;
    }

    // ---- PV: 8 waves, wave q handles j = 8k+q
    float pv[TI];
#pragma unroll
    for (int ti = 0; ti < TI; ++ti) pv[ti] = 0.f;
    {
      const int q = t >> 6, d = t & 63;
      const float* vp = V + (size_t)ho * TOT * DHEAD + d;
      for (int jb = 0; jb < TOT / 8; ++jb) {
        int j = jb * 8 + q;
        float vv = vp[(size_t)j * DHEAD];
#pragma unroll
        for (int ti = 0; ti < TI; ++ti) pv[ti] += sc[ti][j] * vv;
      }
    }
    __syncthreads();
    {
      const int q = t >> 6, d = t & 63;
      float* stg = &sc[0][0];
#pragma unroll
      for (int ti = 0; ti < TI; ++ti) stg[(q * TI + ti) * DHEAD + d] = pv[ti];
    }
    __syncthreads();
    if (t < TI * DHEAD) {
      const float* stg = &sc[0][0];
      int ti = t >> 6, d = t & 63;
      float s = 0.f;
#pragma unroll
      for (int p = 0; p < 8; ++p) s += stg[p * 512 + ti * 64 + d];
      vec[((size_t)(i0 + ti) * BATCH + b) * (NHEAD * DHEAD) + n * DHEAD + d] =
          s * red[ti];
    }
    __syncthreads();
  }
}

// ---------------- attn matrix finalize: mean over batch ---------------------
__global__ __launch_bounds__(256) void attnfin_k(const float* __restrict__ acc,
                                                 float* __restrict__ out)
{
  size_t idx = (size_t)blockIdx.x * 256 + threadIdx.x;
  const size_t S = (size_t)XLEN * TOT;
  float s = acc[idx] + acc[idx + S] + acc[idx + 2 * S] + acc[idx + 3 * S];
  out[idx] = s * (1.0f / 64.0f);
}

// ---------------- LayerNorm (+optional bf16 hi/lo split output) -------------
template<int SPLIT>
__global__ __launch_bounds__(256) void ln_k(const float* __restrict__ in,
                                            const float* __restrict__ g,
                                            const float* __restrict__ bb,
                                            float* __restrict__ out,
                                            unsigned short* __restrict__ oh,
                                            unsigned short* __restrict__ ol)
{
  __shared__ float rbuf[8];
  const int row = blockIdx.x;
  const int t = threadIdx.x;
  const float* p = in + (size_t)row * DM;
  float4 v = *(const float4*)(p + t * 4);
  float s1 = v.x + v.y + v.z + v.w;
  float s2 = v.x * v.x + v.y * v.y + v.z * v.z + v.w * v.w;
#pragma unroll
  for (int off = 32; off; off >>= 1) {
    s1 += __shfl_xor(s1, off);
    s2 += __shfl_xor(s2, off);
  }
  const int wv = t >> 6, lane = t & 63;
  if (lane == 0) { rbuf[wv] = s1; rbuf[4 + wv] = s2; }
  __syncthreads();
  if (t == 0) {
    float a = rbuf[0] + rbuf[1] + rbuf[2] + rbuf[3];
    float b2 = rbuf[4] + rbuf[5] + rbuf[6] + rbuf[7];
    float mu = a * (1.f / DM);
    float var = b2 * (1.f / DM) - mu * mu;
    rbuf[0] = mu;
    rbuf[1] = rsqrtf(var + 1e-5f);
  }
  __syncthreads();
  float mu = rbuf[0], rs = rbuf[1];
  float4 gv = *(const float4*)(g + t * 4);
  float4 bv = *(const float4*)(bb + t * 4);
  float4 o;
  o.x = (v.x - mu) * rs * gv.x + bv.x;
  o.y = (v.y - mu) * rs * gv.y + bv.y;
  o.z = (v.z - mu) * rs * gv.z + bv.z;
  o.w = (v.w - mu) * rs * gv.w + bv.w;
  *(float4*)(out + (size_t)row * DM + t * 4) = o;
  if (SPLIT) {
    ushort4 h, l;
    h.x = bf16rn(o.x); l.x = bf16rn(o.x - bf16tof(h.x));
    h.y = bf16rn(o.y); l.y = bf16rn(o.y - bf16tof(h.y));
    h.z = bf16rn(o.z); l.z = bf16rn(o.z - bf16tof(h.z));
    h.w = bf16rn(o.w); l.w = bf16rn(o.w - bf16tof(h.w));
    *(ushort4*)(oh + (size_t)row * DM + t * 4) = h;
    *(ushort4*)(ol + (size_t)row * DM + t * 4) = l;
  }
}

// ---------------- launch ----------------
extern "C" void kernel_launch(void* const* d_in, const int* in_sizes, int n_in,
                              void* d_out, int out_size, void* d_ws, size_t ws_size,
                              hipStream_t stream) {
  const float* x      = (const float*)d_in[0];
  const float* memory = (const float*)d_in[1];
  const float* pos    = (const float*)d_in[2];
  const float* pbu    = (const float*)d_in[3];
  const float* pbv    = (const float*)d_in[4];
  const float* Wq   = (const float*)d_in[6];
  const float* Wkv  = (const float*)d_in[7];
  const float* Wrel = (const float*)d_in[8];
  const float* Wo   = (const float*)d_in[9];
  const float* ln1g = (const float*)d_in[10];
  const float* ln1b = (const float*)d_in[11];
  const float* W1   = (const float*)d_in[12];
  const float* b1   = (const float*)d_in[13];
  const float* W2   = (const float*)d_in[14];
  const float* b2   = (const float*)d_in[15];
  const float* ln2g = (const float*)d_in[16];
  const float* ln2b = (const float*)d_in[17];

  float* out   = (float*)d_out;                    // [1024,4,1024]
  float* attnm = out + (size_t)XLEN * BATCH * DM;  // [1024,2048]
  float* ws = (float*)d_ws;

  // ---- workspace (float offsets; bf16 arrays cast to ushort*) ----
  // A: 0..8M       c_h(4M) c_l(4M)      -> later vec fp32(4M)@0, t1/t2(4M)@4M
  // B: 8M..16M     pos_h/pos_l          -> Qu(4M)/Qv(4M)        -> ffp_h(8M)
  // C: 16M..20M    Wkv_t h/l (2M), Wq_t h/l (1M), Wrel_t h/l (1M)
  // D: 20M..28M    KT fp32(8M)          -> vec_hl(2M+2M), W1_t h/l(2M+2M)
  // E: 28M..36M    V fp32(8M)           -> W2_t h/l(2M+2M), h_hl(2M+2M)
  // F: 36M..44M    RT fp32(8M)          -> ffp_l(8M)
  // G: 44M..52M    attnacc(8M)          -> h fp32(4M), Wo_t h/l(.5M+.5M)
  unsigned short* c_h   = (unsigned short*)(ws + 0);
  unsigned short* c_l   = (unsigned short*)(ws + 4194304);
  unsigned short* pos_h = (unsigned short*)(ws + 8388608);
  unsigned short* pos_l = (unsigned short*)(ws + 12582912);
  unsigned short* Wkvh  = (unsigned short*)(ws + 16777216);
  unsigned short* Wkvl  = (unsigned short*)(ws + 17825792);
  unsigned short* Wqh   = (unsigned short*)(ws + 18874368);
  unsigned short* Wql   = (unsigned short*)(ws + 19398656);
  unsigned short* Wrelh = (unsigned short*)(ws + 19922944);
  unsigned short* Wrell = (unsigned short*)(ws + 20447232);
  float* KT             = ws + 20971520;
  float* V              = ws + 29360128;
  float* RT             = ws + 37748736;
  float* attnacc        = ws + 46137344;
  float* Qu             = ws + 8388608;   // pos dead after R-GEMM
  float* Qv             = ws + 12582912;
  float* vec            = ws + 0;         // c dead after QKV GEMMs
  float* t1             = ws + 4194304;
  float* t2             = ws + 4194304;   // t1 dead after LN1
  unsigned short* vech  = (unsigned short*)(ws + 20971520);  // KT dead post-attn
  unsigned short* vecl  = (unsigned short*)(ws + 23068672);
  unsigned short* W1h   = (unsigned short*)(ws + 25165824);
  unsigned short* W1l   = (unsigned short*)(ws + 27262976);
  unsigned short* W2h   = (unsigned short*)(ws + 29360128);  // V dead post-attn
  unsigned short* W2l   = (unsigned short*)(ws + 31457280);
  unsigned short* hh    = (unsigned short*)(ws + 33554432);
  unsigned short* hl    = (unsigned short*)(ws + 35651584);
  unsigned short* ffph  = (unsigned short*)(ws + 8388608);   // Qu/Qv dead post-attn
  unsigned short* ffpl  = (unsigned short*)(ws + 37748736);  // RT dead post-attn
  float* h              = ws + 46137344;  // attnacc dead after attnfin
  unsigned short* Woh   = (unsigned short*)(ws + 50331648);
  unsigned short* Wol   = (unsigned short*)(ws + 50855936);

  // 1) splits of activations/weights needed pre-attention
  split2_k<<<8192, 256, 0, stream>>>(memory, x, MEMLEN * BATCH * DM, c_h, c_l);
  split2_k<<<8192, 256, 0, stream>>>(pos, pos, 1 << 30, pos_h, pos_l);
  tsplit_k<<<dim3(16, 32), 256, 0, stream>>>(Wkv, DM, 2048, Wkvh, Wkvl);
  tsplit_k<<<dim3(16, 16), 256, 0, stream>>>(Wq, DM, 1024, Wqh, Wql);
  tsplit_k<<<dim3(16, 16), 256, 0, stream>>>(Wrel, DM, 1024, Wrelh, Wrell);

  // 2) K,V = c@Wkv
  gemm_k<0><<<dim3(16, 64), 256, 0, stream>>>(c_h, c_l, Wkvh, Wkvl, 2048, DM,
                                              nullptr, nullptr, KT, V, nullptr, nullptr);
  // 3) R^T = pos@Wrel
  gemm_k<2><<<dim3(8, 64), 256, 0, stream>>>(pos_h, pos_l, Wrelh, Wrell, 1024, DM,
                                             nullptr, nullptr, RT, nullptr, nullptr, nullptr);
  // 4) Qu,Qv = x@Wq (+bias); x rows are last 4096 rows of c
  gemm_k<1><<<dim3(8, 32), 256, 0, stream>>>(c_h + 4194304, c_l + 4194304, Wqh, Wql,
                                             1024, DM, pbu, pbv, Qu, Qv, nullptr, nullptr);
  // 5) attention
  attn_k<<<dim3(XLEN / TI, BATCH), 512, 0, stream>>>(Qu, Qv, KT, V, RT, vec, attnacc);
  // 6) attn matrix mean over batch
  attnfin_k<<<(XLEN * TOT) / 256, 256, 0, stream>>>(attnacc, attnm);

  // 7) post-attention splits (into regions freed by attn)
  split2_k<<<4096, 256, 0, stream>>>(vec, vec, 1 << 30, vech, vecl);
  tsplit_k<<<dim3(16, 64), 256, 0, stream>>>(W1, DM, DFF, W1h, W1l);
  tsplit_k<<<dim3(64, 16), 256, 0, stream>>>(W2, DFF, 1024, W2h, W2l);
  tsplit_k<<<dim3(16, 16), 256, 0, stream>>>(Wo, DM, 1024, Woh, Wol);

  // 8) attn_out = vec@Wo + x -> t1
  gemm_k<3><<<dim3(8, 32), 256, 0, stream>>>(vech, vecl, Woh, Wol, 1024, DM,
                                             x, nullptr, t1, nullptr, nullptr, nullptr);
  // 9) h = LN1(t1), + bf16 hi/lo
  ln_k<1><<<XLEN * BATCH, 256, 0, stream>>>(t1, ln1g, ln1b, h, hh, hl);
  // 10) ffp = relu(h@W1 + b1) -> bf16 hi/lo directly
  gemm_k<4><<<dim3(32, 32), 256, 0, stream>>>(hh, hl, W1h, W1l, DFF, DM,
                                              b1, nullptr, nullptr, nullptr, ffph, ffpl);
  // 11) t2 = ffp@W2 + b2 + h
  gemm_k<5><<<dim3(8, 32), 256, 0, stream>>>(ffph, ffpl, W2h, W2l, 1024, DFF,
                                             b2, h, t2, nullptr, nullptr, nullptr);
  // 12) out = LN2(t2)
  ln_k<0><<<XLEN * BATCH, 256, 0, stream>>>(t2, ln2g, ln2b, out, nullptr, nullptr);
}